// Round 13
// baseline (173.918 us; speedup 1.0000x reference)
//
#include <hip/hip_runtime.h>
#include <hip/hip_bf16.h>
#include <stdint.h>

#define SEQ    2048
#define BATCH  2
#define DMODEL 1024
#define NHEADS 16
#define HDIM   64
#define MROWS  (BATCH*SEQ)   // 4096

typedef __attribute__((ext_vector_type(8))) short bf16x8;
typedef __attribute__((ext_vector_type(4))) short bf16x4;
typedef __attribute__((ext_vector_type(4))) float f32x4;

__device__ inline void global_to_lds16(const void* g, void* l) {
  __builtin_amdgcn_global_load_lds(
      (const __attribute__((address_space(1))) uint32_t*)g,
      (__attribute__((address_space(3))) uint32_t*)l, 16, 0, 0);
}

__device__ inline unsigned short f2bf_bits(float f) {
  __hip_bfloat16 h = __float2bfloat16(f);
  return *(unsigned short*)&h;
}

// ---- prep: x->bf16 (blocks 0..4095) + W transposes (blocks 4096..8191) ----
__global__ void prep_kernel(const float* __restrict__ x, __hip_bfloat16* __restrict__ xb,
                            const float* __restrict__ Wq, const float* __restrict__ Wk,
                            const float* __restrict__ Wv, const float* __restrict__ Wo,
                            __hip_bfloat16* __restrict__ Wqkv_t, __hip_bfloat16* __restrict__ Wo_t) {
  __shared__ float tile[32][33];
  if (blockIdx.x < 4096) {
    int i = (blockIdx.x * 256 + threadIdx.x) * 4;
    float4 v = *(const float4*)(x + i);
    ushort4 o;
    o.x = f2bf_bits(v.x); o.y = f2bf_bits(v.y);
    o.z = f2bf_bits(v.z); o.w = f2bf_bits(v.w);
    *(ushort4*)(xb + i) = o;
    return;
  }
  int idx = blockIdx.x - 4096;
  int z = idx >> 10;
  int rem = idx & 1023;
  const float* W = (z == 0) ? Wq : (z == 1) ? Wk : (z == 2) ? Wv : Wo;
  __hip_bfloat16* dst = (z < 3) ? (Wqkv_t + (size_t)z * 1024 * 1024) : Wo_t;
  int k0 = (rem & 31) * 32, n0 = (rem >> 5) * 32;
  int tx = threadIdx.x & 31, ty = threadIdx.x >> 5;
#pragma unroll
  for (int r = 0; r < 4; r++)
    tile[ty + r * 8][tx] = W[(size_t)(k0 + ty + r * 8) * 1024 + n0 + tx];
  __syncthreads();
#pragma unroll
  for (int r = 0; r < 4; r++)
    dst[(size_t)(n0 + ty + r * 8) * 1024 + k0 + tx] = __float2bfloat16(tile[tx][ty + r * 8]);
}

// ------ GEMM: C[M][ldc] = A[M][1024]*Wt[N][1024]^T (+bias), BK=64, swizzled LDS ------
// FUSE_VT: for n >= 2048 (V projection) write transposed into Vt[bh][d][s] instead of C.
template <int TN, bool OUT_BF16, int MINW, bool FUSE_VT>
__global__ __launch_bounds__(256, MINW)
void gemm_kernel(const __hip_bfloat16* __restrict__ A, const __hip_bfloat16* __restrict__ Bt,
                 void* __restrict__ C, const float* __restrict__ bias, int ldc,
                 __hip_bfloat16* __restrict__ Vt) {
  __shared__ __hip_bfloat16 Asl[128 * 64];
  __shared__ __hip_bfloat16 Bsl[TN * 64];

  const int t = threadIdx.x;
  const int lane = t & 63;
  const int w = t >> 6;
  constexpr int MI = (TN == 128) ? 4 : 2;
  const int wrow = (TN == 128) ? (w >> 1) * 64 : w * 32;
  const int wcol = (TN == 128) ? (w & 1) * 64 : 0;
  const int m0 = blockIdx.y * 128;
  const int n0 = blockIdx.x * TN;

  f32x4 acc[MI][4];
#pragma unroll
  for (int i = 0; i < MI; i++)
#pragma unroll
    for (int j = 0; j < 4; j++) acc[i][j] = (f32x4){0.f, 0.f, 0.f, 0.f};

  const int srow = lane >> 3;
  const int sjc = (lane & 7) ^ srow;
  const int fm = lane & 15;
  const int g4 = lane >> 4;

  for (int k0 = 0; k0 < 1024; k0 += 64) {
#pragma unroll
    for (int i = 0; i < 4; i++) {
      int seg = i * 4 + w;
      int r = seg * 8 + srow;
      global_to_lds16(A + (size_t)(m0 + r) * 1024 + k0 + sjc * 8,
                      (void*)(Asl + seg * 512 + lane * 8));
    }
#pragma unroll
    for (int i = 0; i < TN / 32; i++) {
      int seg = i * 4 + w;
      int r = seg * 8 + srow;
      global_to_lds16(Bt + (size_t)(n0 + r) * 1024 + k0 + sjc * 8,
                      (void*)(Bsl + seg * 512 + lane * 8));
    }
    __syncthreads();
#pragma unroll
    for (int kb = 0; kb < 2; kb++) {
      bf16x8 af[MI], bfr[4];
#pragma unroll
      for (int mi = 0; mi < MI; mi++) {
        int row = wrow + mi * 16 + fm;
        af[mi] = *(const bf16x8*)(Asl + row * 64 + (((kb * 4 + g4) ^ (row & 7)) << 3));
      }
#pragma unroll
      for (int ni = 0; ni < 4; ni++) {
        int row = wcol + ni * 16 + fm;
        bfr[ni] = *(const bf16x8*)(Bsl + row * 64 + (((kb * 4 + g4) ^ (row & 7)) << 3));
      }
#pragma unroll
      for (int mi = 0; mi < MI; mi++)
#pragma unroll
        for (int ni = 0; ni < 4; ni++)
          acc[mi][ni] = __builtin_amdgcn_mfma_f32_16x16x32_bf16(af[mi], bfr[ni], acc[mi][ni], 0, 0, 0);
    }
    __syncthreads();
  }

  const bool vt_block = FUSE_VT && (n0 >= 2048);
#pragma unroll
  for (int mi = 0; mi < MI; mi++) {
    int mb = m0 + wrow + mi * 16 + g4 * 4;
#pragma unroll
    for (int ni = 0; ni < 4; ni++) {
      int n = n0 + wcol + ni * 16 + fm;
      if (vt_block) {
        int nv = n - 2048;
        int bhh = (mb >> 11) * 16 + (nv >> 6);
        int d = nv & 63;
        int s = mb & 2047;
        unsigned short u[4];
#pragma unroll
        for (int r = 0; r < 4; r++) u[r] = f2bf_bits(acc[mi][ni][r]);
        *(ushort4*)(Vt + ((size_t)bhh * 64 + d) * 2048 + s) = *(const ushort4*)u;
      } else {
        float bv = OUT_BF16 ? 0.f : bias[n];
#pragma unroll
        for (int r = 0; r < 4; r++) {
          if (OUT_BF16)
            ((__hip_bfloat16*)C)[(size_t)(mb + r) * ldc + n] = __float2bfloat16(acc[mi][ni][r]);
          else
            ((float*)C)[(size_t)(mb + r) * ldc + n] = acc[mi][ni][r] + bv;
        }
      }
    }
  }
}

// ---- causal flash attention: 512-thread blocks, 128-row q-tiles, 8 waves share K/V ----
// Grid 512 (16 qt x 32 bh, XCD-local decode) -> 2 blocks/CU = 16 waves/CU.
// Staging-per-compute halved vs 64-row tiles; 64-kt dbuf phases, 32KB LDS.
// Wave w owns q rows [qt*128+w*16, +15] (never crosses a 64-kt boundary):
//   tiles > mtile skipped wave-uniformly; tile == mtile masked; below clear.
// S^T in regs (q=fm, kt=ns*16+g4*4+r = K=16 A-fragment); PV direct from registers.
__global__ __launch_bounds__(512, 4)
void attn_kernel(const __hip_bfloat16* __restrict__ QKV,
                 const __hip_bfloat16* __restrict__ Vt,
                 __hip_bfloat16* __restrict__ ctx) {
  __shared__ __hip_bfloat16 Klds[2][64 * 64];    // [buf][kt][d], chunk j at slot j^(row&7)
  __shared__ __hip_bfloat16 Vlds[2][64 * 64];    // [buf][d][kt], same swizzle

  const int t = threadIdx.x;
  const int lane = t & 63;
  const int w = t >> 6;                    // 0..7
  const int L = blockIdx.x;                // 0..511
  const int bh = (L & 7) + 8 * ((L >> 3) & 3);   // 4 bh per XCD
  const int qt = 15 - (L >> 5);            // 128-row q-tile, longest first
  const int b = bh >> 4, h = bh & 15;
  const int fm = lane & 15;
  const int g4 = lane >> 4;
  const int fk = g4 * 8;
  const size_t rowb = (size_t)b * SEQ;
  const float c = 0.18033688011112042f;    // log2(e)/8

  // staging: each of 512 threads moves one 16B chunk of K and one of V per tile
  const int sr = t >> 3;                   // row 0..63
  const int sjc = (t & 7) ^ (sr & 7);      // swizzled source chunk

  const int qlo = qt * 128 + w * 16;       // wave's q-row window
  const int mtile = (qlo + 15) >> 6;       // the (only) masked tile for this wave
  const int mbase = (w & 3) * 16;          // qlo - mtile*64

  // Q fragments (MFMA B operands), prescaled by c
  bf16x8 qf[2];
  {
    const __hip_bfloat16* qp = QKV + (rowb + qlo + fm) * 3072 + h * 64 + fk;
    bf16x8 r0 = *(const bf16x8*)qp;
    bf16x8 r1 = *(const bf16x8*)(qp + 32);
#pragma unroll
    for (int i = 0; i < 8; i++) {
      float f0 = __uint_as_float(((unsigned)(unsigned short)r0[i]) << 16) * c;
      float f1 = __uint_as_float(((unsigned)(unsigned short)r1[i]) << 16) * c;
      r0[i] = (short)f2bf_bits(f0);
      r1[i] = (short)f2bf_bits(f1);
    }
    qf[0] = r0; qf[1] = r1;
  }

  bf16x4 ones4;
#pragma unroll
  for (int i = 0; i < 4; i++) ones4[i] = (short)0x3F80;

  f32x4 acc[4];
  f32x4 lacc = (f32x4){0.f, 0.f, 0.f, 0.f};
#pragma unroll
  for (int d = 0; d < 4; d++) acc[d] = (f32x4){0.f, 0.f, 0.f, 0.f};

  auto stage = [&](int kts, int bufi) {
    const int kt0 = kts * 64;
    global_to_lds16(QKV + (rowb + kt0 + sr) * 3072 + 1024 + h * 64 + sjc * 8,
                    (void*)(&Klds[bufi][0] + t * 8));
    global_to_lds16(Vt + ((size_t)bh * 64 + sr) * 2048 + kt0 + sjc * 8,
                    (void*)(&Vlds[bufi][0] + t * 8));
  };

  const int lastt = 2 * qt + 1;
  stage(0, 0);
  for (int kts = 0; kts <= lastt; ++kts) {
    __syncthreads();                       // drains tile-kts loads (issued 1 phase ago)
    if (kts < lastt) stage(kts + 1, (kts + 1) & 1);
    if (kts > mtile) continue;             // wave-uniform: this wave is done computing
    const __hip_bfloat16* Kb = &Klds[kts & 1][0];
    const __hip_bfloat16* Vb = &Vlds[kts & 1][0];

    // S^T = K Q^T (kf loads in consumption order)
    f32x4 st[4];
#pragma unroll
    for (int ns = 0; ns < 4; ns++) st[ns] = (f32x4){0.f, 0.f, 0.f, 0.f};
#pragma unroll
    for (int kk = 0; kk < 2; kk++) {
#pragma unroll
      for (int ns = 0; ns < 4; ns++) {
        bf16x8 kf = *(const bf16x8*)(Kb + (ns * 16 + fm) * 64 + (((kk * 4 + g4) ^ (fm & 7)) << 3));
        st[ns] = __builtin_amdgcn_mfma_f32_16x16x32_bf16(kf, qf[kk], st[ns], 0, 0, 0);
      }
    }

    // V B-fragments for K=16 MFMA (after QK)
    bf16x4 vf[4][4];   // [dd][ns]
#pragma unroll
    for (int dd = 0; dd < 4; dd++)
#pragma unroll
      for (int ns = 0; ns < 4; ns++)
        vf[dd][ns] = *(const bf16x4*)(Vb + (dd * 16 + fm) * 64 +
                                      (((2 * ns + (g4 >> 1)) ^ (fm & 7)) << 3) + (g4 & 1) * 4);

    // exp2 -> truncate-pack (v_perm) -> PV + rowsum MFMAs, all in registers
    const bool diag = (kts == mtile);
#pragma unroll
    for (int ns = 0; ns < 4; ns++) {
      float e[4];
#pragma unroll
      for (int r = 0; r < 4; r++) {
        float p = __builtin_amdgcn_exp2f(st[ns][r]);
        if (diag) {
          int ktl = ns * 16 + g4 * 4 + r;
          p = (ktl > mbase + fm) ? 0.f : p;
        }
        e[r] = p;
      }
      unsigned lo = __builtin_amdgcn_perm(__builtin_bit_cast(unsigned, e[1]),
                                          __builtin_bit_cast(unsigned, e[0]), 0x07060302u);
      unsigned hi = __builtin_amdgcn_perm(__builtin_bit_cast(unsigned, e[3]),
                                          __builtin_bit_cast(unsigned, e[2]), 0x07060302u);
      uint2 pp; pp.x = lo; pp.y = hi;
      bf16x4 pf = __builtin_bit_cast(bf16x4, pp);
      lacc = __builtin_amdgcn_mfma_f32_16x16x16bf16_1k(pf, ones4, lacc, 0, 0, 0);
#pragma unroll
      for (int dd = 0; dd < 4; dd++)
        acc[dd] = __builtin_amdgcn_mfma_f32_16x16x16bf16_1k(pf, vf[dd][ns], acc[dd], 0, 0, 0);
    }
  }

  // epilogue: ctx = acc * rcp(l)   (D rows q = qlo + g4*4 + r, cols d = dd*16 + fm)
  float rl[4];
#pragma unroll
  for (int r = 0; r < 4; r++) rl[r] = __builtin_amdgcn_rcpf(lacc[r]);
#pragma unroll
  for (int dd = 0; dd < 4; dd++)
#pragma unroll
    for (int r = 0; r < 4; r++) {
      int q = qlo + g4 * 4 + r;
      ctx[(rowb + q) * 1024 + h * 64 + dd * 16 + fm] =
          __float2bfloat16(acc[dd][r] * rl[r]);
    }
}

// ---------------- launch ----------------
extern "C" void kernel_launch(void* const* d_in, const int* in_sizes, int n_in,
                              void* d_out, int out_size, void* d_ws, size_t ws_size,
                              hipStream_t stream) {
  const float* x  = (const float*)d_in[0];
  const float* Wq = (const float*)d_in[1];
  const float* Wk = (const float*)d_in[2];
  const float* Wv = (const float*)d_in[3];
  const float* Wo = (const float*)d_in[4];
  const float* bo = (const float*)d_in[5];
  float* out = (float*)d_out;

  char* ws = (char*)d_ws;
  __hip_bfloat16* xb     = (__hip_bfloat16*)(ws);                      // 8 MiB
  __hip_bfloat16* Wqkv_t = (__hip_bfloat16*)(ws + (8ull  << 20));      // 6 MiB
  __hip_bfloat16* Wo_t   = (__hip_bfloat16*)(ws + (14ull << 20));      // 2 MiB
  __hip_bfloat16* QKV    = (__hip_bfloat16*)(ws + (16ull << 20));      // 24 MiB (V cols unused)
  __hip_bfloat16* ctxb   = (__hip_bfloat16*)(ws + (40ull << 20));      // 8 MiB
  __hip_bfloat16* Vt     = (__hip_bfloat16*)(ws + (48ull << 20));      // 8 MiB

  prep_kernel<<<dim3(8192), dim3(256), 0, stream>>>(x, xb, Wq, Wk, Wv, Wo, Wqkv_t, Wo_t);
  gemm_kernel<128, true, 3, true><<<dim3(24, 32), dim3(256), 0, stream>>>(
      xb, Wqkv_t, (void*)QKV, nullptr, 3072, Vt);
  attn_kernel<<<dim3(512), dim3(512), 0, stream>>>(QKV, Vt, ctxb);
  gemm_kernel<64, false, 2, false><<<dim3(16, 32), dim3(256), 0, stream>>>(
      ctxb, Wo_t, (void*)out, bo, 1024, nullptr);
}

// Round 14
// 163.049 us; speedup vs baseline: 1.0667x; 1.0667x over previous
//
#include <hip/hip_runtime.h>
#include <hip/hip_bf16.h>
#include <stdint.h>

#define SEQ    2048
#define BATCH  2
#define DMODEL 1024
#define NHEADS 16
#define HDIM   64
#define MROWS  (BATCH*SEQ)   // 4096

typedef __attribute__((ext_vector_type(8))) short bf16x8;
typedef __attribute__((ext_vector_type(4))) short bf16x4;
typedef __attribute__((ext_vector_type(4))) float f32x4;

__device__ inline void global_to_lds16(const void* g, void* l) {
  __builtin_amdgcn_global_load_lds(
      (const __attribute__((address_space(1))) uint32_t*)g,
      (__attribute__((address_space(3))) uint32_t*)l, 16, 0, 0);
}

__device__ inline unsigned short f2bf_bits(float f) {
  __hip_bfloat16 h = __float2bfloat16(f);
  return *(unsigned short*)&h;
}

// ---- prep: x->bf16 (blocks 0..4095) + W transposes (blocks 4096..8191) ----
__global__ void prep_kernel(const float* __restrict__ x, __hip_bfloat16* __restrict__ xb,
                            const float* __restrict__ Wq, const float* __restrict__ Wk,
                            const float* __restrict__ Wv, const float* __restrict__ Wo,
                            __hip_bfloat16* __restrict__ Wqkv_t, __hip_bfloat16* __restrict__ Wo_t) {
  __shared__ float tile[32][33];
  if (blockIdx.x < 4096) {
    int i = (blockIdx.x * 256 + threadIdx.x) * 4;
    float4 v = *(const float4*)(x + i);
    ushort4 o;
    o.x = f2bf_bits(v.x); o.y = f2bf_bits(v.y);
    o.z = f2bf_bits(v.z); o.w = f2bf_bits(v.w);
    *(ushort4*)(xb + i) = o;
    return;
  }
  int idx = blockIdx.x - 4096;
  int z = idx >> 10;
  int rem = idx & 1023;
  const float* W = (z == 0) ? Wq : (z == 1) ? Wk : (z == 2) ? Wv : Wo;
  __hip_bfloat16* dst = (z < 3) ? (Wqkv_t + (size_t)z * 1024 * 1024) : Wo_t;
  int k0 = (rem & 31) * 32, n0 = (rem >> 5) * 32;
  int tx = threadIdx.x & 31, ty = threadIdx.x >> 5;
#pragma unroll
  for (int r = 0; r < 4; r++)
    tile[ty + r * 8][tx] = W[(size_t)(k0 + ty + r * 8) * 1024 + n0 + tx];
  __syncthreads();
#pragma unroll
  for (int r = 0; r < 4; r++)
    dst[(size_t)(n0 + ty + r * 8) * 1024 + k0 + tx] = __float2bfloat16(tile[tx][ty + r * 8]);
}

// ------ GEMM: C[M][ldc] = A[M][1024]*Wt[N][1024]^T (+bias), BK=64, swizzled LDS ------
// FUSE_VT: for n >= 2048 (V projection) write transposed into Vt[bh][d][s] instead of C.
template <int TN, bool OUT_BF16, int MINW, bool FUSE_VT>
__global__ __launch_bounds__(256, MINW)
void gemm_kernel(const __hip_bfloat16* __restrict__ A, const __hip_bfloat16* __restrict__ Bt,
                 void* __restrict__ C, const float* __restrict__ bias, int ldc,
                 __hip_bfloat16* __restrict__ Vt) {
  __shared__ __hip_bfloat16 Asl[128 * 64];
  __shared__ __hip_bfloat16 Bsl[TN * 64];

  const int t = threadIdx.x;
  const int lane = t & 63;
  const int w = t >> 6;
  constexpr int MI = (TN == 128) ? 4 : 2;
  const int wrow = (TN == 128) ? (w >> 1) * 64 : w * 32;
  const int wcol = (TN == 128) ? (w & 1) * 64 : 0;
  const int m0 = blockIdx.y * 128;
  const int n0 = blockIdx.x * TN;

  f32x4 acc[MI][4];
#pragma unroll
  for (int i = 0; i < MI; i++)
#pragma unroll
    for (int j = 0; j < 4; j++) acc[i][j] = (f32x4){0.f, 0.f, 0.f, 0.f};

  const int srow = lane >> 3;
  const int sjc = (lane & 7) ^ srow;
  const int fm = lane & 15;
  const int g4 = lane >> 4;

  for (int k0 = 0; k0 < 1024; k0 += 64) {
#pragma unroll
    for (int i = 0; i < 4; i++) {
      int seg = i * 4 + w;
      int r = seg * 8 + srow;
      global_to_lds16(A + (size_t)(m0 + r) * 1024 + k0 + sjc * 8,
                      (void*)(Asl + seg * 512 + lane * 8));
    }
#pragma unroll
    for (int i = 0; i < TN / 32; i++) {
      int seg = i * 4 + w;
      int r = seg * 8 + srow;
      global_to_lds16(Bt + (size_t)(n0 + r) * 1024 + k0 + sjc * 8,
                      (void*)(Bsl + seg * 512 + lane * 8));
    }
    __syncthreads();
#pragma unroll
    for (int kb = 0; kb < 2; kb++) {
      bf16x8 af[MI], bfr[4];
#pragma unroll
      for (int mi = 0; mi < MI; mi++) {
        int row = wrow + mi * 16 + fm;
        af[mi] = *(const bf16x8*)(Asl + row * 64 + (((kb * 4 + g4) ^ (row & 7)) << 3));
      }
#pragma unroll
      for (int ni = 0; ni < 4; ni++) {
        int row = wcol + ni * 16 + fm;
        bfr[ni] = *(const bf16x8*)(Bsl + row * 64 + (((kb * 4 + g4) ^ (row & 7)) << 3));
      }
#pragma unroll
      for (int mi = 0; mi < MI; mi++)
#pragma unroll
        for (int ni = 0; ni < 4; ni++)
          acc[mi][ni] = __builtin_amdgcn_mfma_f32_16x16x32_bf16(af[mi], bfr[ni], acc[mi][ni], 0, 0, 0);
    }
    __syncthreads();
  }

  const bool vt_block = FUSE_VT && (n0 >= 2048);
#pragma unroll
  for (int mi = 0; mi < MI; mi++) {
    int mb = m0 + wrow + mi * 16 + g4 * 4;
#pragma unroll
    for (int ni = 0; ni < 4; ni++) {
      int n = n0 + wcol + ni * 16 + fm;
      if (vt_block) {
        int nv = n - 2048;
        int bhh = (mb >> 11) * 16 + (nv >> 6);
        int d = nv & 63;
        int s = mb & 2047;
        unsigned short u[4];
#pragma unroll
        for (int r = 0; r < 4; r++) u[r] = f2bf_bits(acc[mi][ni][r]);
        *(ushort4*)(Vt + ((size_t)bhh * 64 + d) * 2048 + s) = *(const ushort4*)u;
      } else {
        float bv = OUT_BF16 ? 0.f : bias[n];
#pragma unroll
        for (int r = 0; r < 4; r++) {
          if (OUT_BF16)
            ((__hip_bfloat16*)C)[(size_t)(mb + r) * ldc + n] = __float2bfloat16(acc[mi][ni][r]);
          else
            ((float*)C)[(size_t)(mb + r) * ldc + n] = acc[mi][ni][r] + bv;
        }
      }
    }
  }
}

// ---- causal flash attention: paired q-tiles, register-staged fragments ----
// Key restructure: per phase, (1) ds_read ALL fragments for tile kts into registers,
// (2) THEN issue the global_load_lds prefetch for kts+1, (3) compute purely from
// registers (no DS ops after the prefetch -> compiler cannot insert a vmcnt(0)
// drain mid-phase; the drain lands at the barrier after a full compute phase).
// Paired scheduling (jb, 31-jb) + XCD-local decode keep staging L2-resident and
// per-CU phase counts uniform (49). Grid 512 = 2 blocks/CU, fully resident.
__global__ __launch_bounds__(256, 2)
void attn_kernel(const __hip_bfloat16* __restrict__ QKV,
                 const __hip_bfloat16* __restrict__ Vt,
                 __hip_bfloat16* __restrict__ ctx) {
  __shared__ __hip_bfloat16 Klds[2][64 * 64];    // [buf][kt][d], chunk j at slot j^(row&7)
  __shared__ __hip_bfloat16 Vlds[2][64 * 64];    // [buf][d][kt], same swizzle

  const int t = threadIdx.x;
  const int lane = t & 63;
  const int w = t >> 6;                    // 0..3
  const int L = blockIdx.x;                // 0..511
  const int bh = (L & 7) + 8 * ((L >> 3) & 3);   // 4 bh per XCD (wgid%8 heuristic)
  const int jraw = L >> 5;                       // 0..15
  const int jb = (jraw < 8) ? jraw : 23 - jraw;  // co-resident complementary pairs
  const int qtab[2] = { jb, 31 - jb };
  const int b = bh >> 4, h = bh & 15;
  const int fm = lane & 15;
  const int g4 = lane >> 4;
  const int fk = g4 * 8;
  const size_t rowb = (size_t)b * SEQ;
  const float c = 0.18033688011112042f;    // log2(e)/8

  const int krr = lane >> 3;
  const int kjc = (lane & 7) ^ krr;        // staging swizzle

  // Q fragments (MFMA B operands), prescaled by c
  bf16x8 qf[2][2];
#pragma unroll
  for (int hh = 0; hh < 2; hh++) {
    const __hip_bfloat16* qp = QKV + (rowb + qtab[hh] * 64 + w * 16 + fm) * 3072 + h * 64 + fk;
    bf16x8 r0 = *(const bf16x8*)qp;
    bf16x8 r1 = *(const bf16x8*)(qp + 32);
#pragma unroll
    for (int i = 0; i < 8; i++) {
      float f0 = __uint_as_float(((unsigned)(unsigned short)r0[i]) << 16) * c;
      float f1 = __uint_as_float(((unsigned)(unsigned short)r1[i]) << 16) * c;
      r0[i] = (short)f2bf_bits(f0);
      r1[i] = (short)f2bf_bits(f1);
    }
    qf[hh][0] = r0; qf[hh][1] = r1;
  }

  bf16x4 ones4;
#pragma unroll
  for (int i = 0; i < 4; i++) ones4[i] = (short)0x3F80;

  f32x4 acc[2][4];
  f32x4 lacc[2];
#pragma unroll
  for (int hh = 0; hh < 2; hh++) {
    lacc[hh] = (f32x4){0.f, 0.f, 0.f, 0.f};
#pragma unroll
    for (int d = 0; d < 4; d++) acc[hh][d] = (f32x4){0.f, 0.f, 0.f, 0.f};
  }

  auto stage = [&](int kts, int bufi) {
    const int kt0 = kts * 64;
#pragma unroll
    for (int i = 0; i < 2; i++) {
      int seg = w + i * 4;                 // 0..7
      int r = seg * 8 + krr;               // 0..63
      global_to_lds16(QKV + (rowb + kt0 + r) * 3072 + 1024 + h * 64 + kjc * 8,
                      (void*)(&Klds[bufi][0] + seg * 512 + lane * 8));
      global_to_lds16(Vt + ((size_t)bh * 64 + r) * 2048 + kt0 + kjc * 8,
                      (void*)(&Vlds[bufi][0] + seg * 512 + lane * 8));
    }
  };

  const int lastt = qtab[1];
  stage(0, 0);
  for (int kts = 0; kts <= lastt; ++kts) {
    __syncthreads();                       // drains prefetch issued last phase
    const __hip_bfloat16* Kb = &Klds[kts & 1][0];
    const __hip_bfloat16* Vb = &Vlds[kts & 1][0];
    const bool act0 = (kts <= qtab[0]);

    // (1) ALL fragments for this tile -> registers (kf then vf, consumption order)
    bf16x8 kf[2][4];
#pragma unroll
    for (int kk = 0; kk < 2; kk++)
#pragma unroll
      for (int ns = 0; ns < 4; ns++)
        kf[kk][ns] = *(const bf16x8*)(Kb + (ns * 16 + fm) * 64 + (((kk * 4 + g4) ^ (fm & 7)) << 3));
    bf16x4 vf[4][4];
#pragma unroll
    for (int dd = 0; dd < 4; dd++)
#pragma unroll
      for (int ns = 0; ns < 4; ns++)
        vf[dd][ns] = *(const bf16x4*)(Vb + (dd * 16 + fm) * 64 +
                                      (((2 * ns + (g4 >> 1)) ^ (fm & 7)) << 3) + (g4 & 1) * 4);

    // (2) prefetch next tile into the other buffer (no DS ops follow this phase)
    if (kts < lastt) stage(kts + 1, (kts + 1) & 1);

    // (3) compute purely from registers
    f32x4 st1[4], st0[4];
#pragma unroll
    for (int ns = 0; ns < 4; ns++) {
      st1[ns] = (f32x4){0.f, 0.f, 0.f, 0.f};
      st0[ns] = (f32x4){0.f, 0.f, 0.f, 0.f};
    }
#pragma unroll
    for (int kk = 0; kk < 2; kk++) {
#pragma unroll
      for (int ns = 0; ns < 4; ns++)
        st1[ns] = __builtin_amdgcn_mfma_f32_16x16x32_bf16(kf[kk][ns], qf[1][kk], st1[ns], 0, 0, 0);
      if (act0)
#pragma unroll
        for (int ns = 0; ns < 4; ns++)
          st0[ns] = __builtin_amdgcn_mfma_f32_16x16x32_bf16(kf[kk][ns], qf[0][kk], st0[ns], 0, 0, 0);
    }

    auto half = [&](const f32x4 (&st)[4], int hh) {
      const bool diag = (kts == qtab[hh]);
#pragma unroll
      for (int ns = 0; ns < 4; ns++) {
        float e[4];
#pragma unroll
        for (int r = 0; r < 4; r++) {
          float p = __builtin_amdgcn_exp2f(st[ns][r]);
          if (diag) {
            int ktl = ns * 16 + g4 * 4 + r;
            p = (ktl > w * 16 + fm) ? 0.f : p;
          }
          e[r] = p;
        }
        unsigned lo = __builtin_amdgcn_perm(__builtin_bit_cast(unsigned, e[1]),
                                            __builtin_bit_cast(unsigned, e[0]), 0x07060302u);
        unsigned hi = __builtin_amdgcn_perm(__builtin_bit_cast(unsigned, e[3]),
                                            __builtin_bit_cast(unsigned, e[2]), 0x07060302u);
        uint2 pp; pp.x = lo; pp.y = hi;
        bf16x4 pf = __builtin_bit_cast(bf16x4, pp);
        lacc[hh] = __builtin_amdgcn_mfma_f32_16x16x16bf16_1k(pf, ones4, lacc[hh], 0, 0, 0);
#pragma unroll
        for (int dd = 0; dd < 4; dd++)
          acc[hh][dd] = __builtin_amdgcn_mfma_f32_16x16x16bf16_1k(pf, vf[dd][ns], acc[hh][dd], 0, 0, 0);
      }
    };
    half(st1, 1);
    if (act0) half(st0, 0);
  }

  // epilogue: ctx = acc * rcp(l)
#pragma unroll
  for (int hh = 0; hh < 2; hh++) {
    float rl[4];
#pragma unroll
    for (int r = 0; r < 4; r++) rl[r] = __builtin_amdgcn_rcpf(lacc[hh][r]);
#pragma unroll
    for (int dd = 0; dd < 4; dd++)
#pragma unroll
      for (int r = 0; r < 4; r++) {
        int q = qtab[hh] * 64 + w * 16 + g4 * 4 + r;
        ctx[(rowb + q) * 1024 + h * 64 + dd * 16 + fm] =
            __float2bfloat16(acc[hh][dd][r] * rl[r]);
      }
  }
}

// ---------------- launch ----------------
extern "C" void kernel_launch(void* const* d_in, const int* in_sizes, int n_in,
                              void* d_out, int out_size, void* d_ws, size_t ws_size,
                              hipStream_t stream) {
  const float* x  = (const float*)d_in[0];
  const float* Wq = (const float*)d_in[1];
  const float* Wk = (const float*)d_in[2];
  const float* Wv = (const float*)d_in[3];
  const float* Wo = (const float*)d_in[4];
  const float* bo = (const float*)d_in[5];
  float* out = (float*)d_out;

  char* ws = (char*)d_ws;
  __hip_bfloat16* xb     = (__hip_bfloat16*)(ws);                      // 8 MiB
  __hip_bfloat16* Wqkv_t = (__hip_bfloat16*)(ws + (8ull  << 20));      // 6 MiB
  __hip_bfloat16* Wo_t   = (__hip_bfloat16*)(ws + (14ull << 20));      // 2 MiB
  __hip_bfloat16* QKV    = (__hip_bfloat16*)(ws + (16ull << 20));      // 24 MiB (V cols unused)
  __hip_bfloat16* ctxb   = (__hip_bfloat16*)(ws + (40ull << 20));      // 8 MiB
  __hip_bfloat16* Vt     = (__hip_bfloat16*)(ws + (48ull << 20));      // 8 MiB

  prep_kernel<<<dim3(8192), dim3(256), 0, stream>>>(x, xb, Wq, Wk, Wv, Wo, Wqkv_t, Wo_t);
  gemm_kernel<128, true, 3, true><<<dim3(24, 32), dim3(256), 0, stream>>>(
      xb, Wqkv_t, (void*)QKV, nullptr, 3072, Vt);
  attn_kernel<<<dim3(512), dim3(256), 0, stream>>>(QKV, Vt, ctxb);
  gemm_kernel<64, false, 2, false><<<dim3(16, 32), dim3(256), 0, stream>>>(
      ctxb, Wo_t, (void*)out, bo, 1024, nullptr);
}

// Round 15
// 162.808 us; speedup vs baseline: 1.0682x; 1.0015x over previous
//
#include <hip/hip_runtime.h>
#include <hip/hip_bf16.h>
#include <stdint.h>

#define SEQ    2048
#define BATCH  2
#define DMODEL 1024
#define NHEADS 16
#define HDIM   64
#define MROWS  (BATCH*SEQ)   // 4096

typedef __attribute__((ext_vector_type(8))) short bf16x8;
typedef __attribute__((ext_vector_type(4))) short bf16x4;
typedef __attribute__((ext_vector_type(4))) float f32x4;

__device__ inline void global_to_lds16(const void* g, void* l) {
  __builtin_amdgcn_global_load_lds(
      (const __attribute__((address_space(1))) uint32_t*)g,
      (__attribute__((address_space(3))) uint32_t*)l, 16, 0, 0);
}

__device__ inline unsigned short f2bf_bits(float f) {
  __hip_bfloat16 h = __float2bfloat16(f);
  return *(unsigned short*)&h;
}

// ---- prep: x->bf16 (blocks 0..4095) + W transposes (blocks 4096..8191) ----
__global__ void prep_kernel(const float* __restrict__ x, __hip_bfloat16* __restrict__ xb,
                            const float* __restrict__ Wq, const float* __restrict__ Wk,
                            const float* __restrict__ Wv, const float* __restrict__ Wo,
                            __hip_bfloat16* __restrict__ Wqkv_t, __hip_bfloat16* __restrict__ Wo_t) {
  __shared__ float tile[32][33];
  if (blockIdx.x < 4096) {
    int i = (blockIdx.x * 256 + threadIdx.x) * 4;
    float4 v = *(const float4*)(x + i);
    ushort4 o;
    o.x = f2bf_bits(v.x); o.y = f2bf_bits(v.y);
    o.z = f2bf_bits(v.z); o.w = f2bf_bits(v.w);
    *(ushort4*)(xb + i) = o;
    return;
  }
  int idx = blockIdx.x - 4096;
  int z = idx >> 10;
  int rem = idx & 1023;
  const float* W = (z == 0) ? Wq : (z == 1) ? Wk : (z == 2) ? Wv : Wo;
  __hip_bfloat16* dst = (z < 3) ? (Wqkv_t + (size_t)z * 1024 * 1024) : Wo_t;
  int k0 = (rem & 31) * 32, n0 = (rem >> 5) * 32;
  int tx = threadIdx.x & 31, ty = threadIdx.x >> 5;
#pragma unroll
  for (int r = 0; r < 4; r++)
    tile[ty + r * 8][tx] = W[(size_t)(k0 + ty + r * 8) * 1024 + n0 + tx];
  __syncthreads();
#pragma unroll
  for (int r = 0; r < 4; r++)
    dst[(size_t)(n0 + ty + r * 8) * 1024 + k0 + tx] = __float2bfloat16(tile[tx][ty + r * 8]);
}

// ------ GEMM: C[M][ldc] = A[M][1024]*Wt[N][1024]^T (+bias), BK=64, dbuf LDS ------
// Register-staged phases (R14-validated pattern): per k-phase, (1) ds_read ALL
// fragments for this k-tile into registers, (2) THEN issue global_load_lds prefetch
// for k+64 into the other buffer, (3) compute purely from registers. No DS op after
// the prefetch -> no mid-phase vmcnt(0) drain; the drain lands at the barrier after
// a full compute phase of load flight time.
// FUSE_VT: for n >= 2048 (V projection) write transposed into Vt[bh][d][s] instead of C.
template <int TN, bool OUT_BF16, int MINW, bool FUSE_VT>
__global__ __launch_bounds__(256, MINW)
void gemm_kernel(const __hip_bfloat16* __restrict__ A, const __hip_bfloat16* __restrict__ Bt,
                 void* __restrict__ C, const float* __restrict__ bias, int ldc,
                 __hip_bfloat16* __restrict__ Vt) {
  __shared__ __hip_bfloat16 Asl[2][128 * 64];
  __shared__ __hip_bfloat16 Bsl[2][TN * 64];

  const int t = threadIdx.x;
  const int lane = t & 63;
  const int w = t >> 6;
  constexpr int MI = (TN == 128) ? 4 : 2;
  const int wrow = (TN == 128) ? (w >> 1) * 64 : w * 32;
  const int wcol = (TN == 128) ? (w & 1) * 64 : 0;
  const int m0 = blockIdx.y * 128;
  const int n0 = blockIdx.x * TN;

  f32x4 acc[MI][4];
#pragma unroll
  for (int i = 0; i < MI; i++)
#pragma unroll
    for (int j = 0; j < 4; j++) acc[i][j] = (f32x4){0.f, 0.f, 0.f, 0.f};

  const int srow = lane >> 3;
  const int sjc = (lane & 7) ^ srow;
  const int fm = lane & 15;
  const int g4 = lane >> 4;

  auto stage = [&](int k0, int bufi) {
#pragma unroll
    for (int i = 0; i < 4; i++) {
      int seg = i * 4 + w;
      int r = seg * 8 + srow;
      global_to_lds16(A + (size_t)(m0 + r) * 1024 + k0 + sjc * 8,
                      (void*)(&Asl[bufi][0] + seg * 512 + lane * 8));
    }
#pragma unroll
    for (int i = 0; i < TN / 32; i++) {
      int seg = i * 4 + w;
      int r = seg * 8 + srow;
      global_to_lds16(Bt + (size_t)(n0 + r) * 1024 + k0 + sjc * 8,
                      (void*)(&Bsl[bufi][0] + seg * 512 + lane * 8));
    }
  };

  stage(0, 0);
  for (int k0 = 0; k0 < 1024; k0 += 64) {
    const int buf = (k0 >> 6) & 1;
    __syncthreads();                       // drains prefetch issued last phase

    // (1) ALL fragments for this k-tile -> registers
    bf16x8 af[2][MI], bfr[2][4];
#pragma unroll
    for (int kb = 0; kb < 2; kb++) {
#pragma unroll
      for (int mi = 0; mi < MI; mi++) {
        int row = wrow + mi * 16 + fm;
        af[kb][mi] = *(const bf16x8*)(&Asl[buf][0] + row * 64 + (((kb * 4 + g4) ^ (row & 7)) << 3));
      }
#pragma unroll
      for (int ni = 0; ni < 4; ni++) {
        int row = wcol + ni * 16 + fm;
        bfr[kb][ni] = *(const bf16x8*)(&Bsl[buf][0] + row * 64 + (((kb * 4 + g4) ^ (row & 7)) << 3));
      }
    }

    // (2) prefetch next k-tile into the other buffer
    if (k0 + 64 < 1024) stage(k0 + 64, buf ^ 1);

    // (3) compute purely from registers
#pragma unroll
    for (int kb = 0; kb < 2; kb++)
#pragma unroll
      for (int mi = 0; mi < MI; mi++)
#pragma unroll
        for (int ni = 0; ni < 4; ni++)
          acc[mi][ni] = __builtin_amdgcn_mfma_f32_16x16x32_bf16(af[kb][mi], bfr[kb][ni], acc[mi][ni], 0, 0, 0);
  }

  const bool vt_block = FUSE_VT && (n0 >= 2048);
#pragma unroll
  for (int mi = 0; mi < MI; mi++) {
    int mb = m0 + wrow + mi * 16 + g4 * 4;
#pragma unroll
    for (int ni = 0; ni < 4; ni++) {
      int n = n0 + wcol + ni * 16 + fm;
      if (vt_block) {
        int nv = n - 2048;
        int bhh = (mb >> 11) * 16 + (nv >> 6);
        int d = nv & 63;
        int s = mb & 2047;
        unsigned short u[4];
#pragma unroll
        for (int r = 0; r < 4; r++) u[r] = f2bf_bits(acc[mi][ni][r]);
        *(ushort4*)(Vt + ((size_t)bhh * 64 + d) * 2048 + s) = *(const ushort4*)u;
      } else {
        float bv = OUT_BF16 ? 0.f : bias[n];
#pragma unroll
        for (int r = 0; r < 4; r++) {
          if (OUT_BF16)
            ((__hip_bfloat16*)C)[(size_t)(mb + r) * ldc + n] = __float2bfloat16(acc[mi][ni][r]);
          else
            ((float*)C)[(size_t)(mb + r) * ldc + n] = acc[mi][ni][r] + bv;
        }
      }
    }
  }
}

// ---- causal flash attention: paired q-tiles, register-staged fragments (R14) ----
__global__ __launch_bounds__(256, 2)
void attn_kernel(const __hip_bfloat16* __restrict__ QKV,
                 const __hip_bfloat16* __restrict__ Vt,
                 __hip_bfloat16* __restrict__ ctx) {
  __shared__ __hip_bfloat16 Klds[2][64 * 64];    // [buf][kt][d], chunk j at slot j^(row&7)
  __shared__ __hip_bfloat16 Vlds[2][64 * 64];    // [buf][d][kt], same swizzle

  const int t = threadIdx.x;
  const int lane = t & 63;
  const int w = t >> 6;                    // 0..3
  const int L = blockIdx.x;                // 0..511
  const int bh = (L & 7) + 8 * ((L >> 3) & 3);   // 4 bh per XCD (wgid%8 heuristic)
  const int jraw = L >> 5;                       // 0..15
  const int jb = (jraw < 8) ? jraw : 23 - jraw;  // co-resident complementary pairs
  const int qtab[2] = { jb, 31 - jb };
  const int b = bh >> 4, h = bh & 15;
  const int fm = lane & 15;
  const int g4 = lane >> 4;
  const int fk = g4 * 8;
  const size_t rowb = (size_t)b * SEQ;
  const float c = 0.18033688011112042f;    // log2(e)/8

  const int krr = lane >> 3;
  const int kjc = (lane & 7) ^ krr;        // staging swizzle

  // Q fragments (MFMA B operands), prescaled by c
  bf16x8 qf[2][2];
#pragma unroll
  for (int hh = 0; hh < 2; hh++) {
    const __hip_bfloat16* qp = QKV + (rowb + qtab[hh] * 64 + w * 16 + fm) * 3072 + h * 64 + fk;
    bf16x8 r0 = *(const bf16x8*)qp;
    bf16x8 r1 = *(const bf16x8*)(qp + 32);
#pragma unroll
    for (int i = 0; i < 8; i++) {
      float f0 = __uint_as_float(((unsigned)(unsigned short)r0[i]) << 16) * c;
      float f1 = __uint_as_float(((unsigned)(unsigned short)r1[i]) << 16) * c;
      r0[i] = (short)f2bf_bits(f0);
      r1[i] = (short)f2bf_bits(f1);
    }
    qf[hh][0] = r0; qf[hh][1] = r1;
  }

  bf16x4 ones4;
#pragma unroll
  for (int i = 0; i < 4; i++) ones4[i] = (short)0x3F80;

  f32x4 acc[2][4];
  f32x4 lacc[2];
#pragma unroll
  for (int hh = 0; hh < 2; hh++) {
    lacc[hh] = (f32x4){0.f, 0.f, 0.f, 0.f};
#pragma unroll
    for (int d = 0; d < 4; d++) acc[hh][d] = (f32x4){0.f, 0.f, 0.f, 0.f};
  }

  auto stage = [&](int kts, int bufi) {
    const int kt0 = kts * 64;
#pragma unroll
    for (int i = 0; i < 2; i++) {
      int seg = w + i * 4;                 // 0..7
      int r = seg * 8 + krr;               // 0..63
      global_to_lds16(QKV + (rowb + kt0 + r) * 3072 + 1024 + h * 64 + kjc * 8,
                      (void*)(&Klds[bufi][0] + seg * 512 + lane * 8));
      global_to_lds16(Vt + ((size_t)bh * 64 + r) * 2048 + kt0 + kjc * 8,
                      (void*)(&Vlds[bufi][0] + seg * 512 + lane * 8));
    }
  };

  const int lastt = qtab[1];
  stage(0, 0);
  for (int kts = 0; kts <= lastt; ++kts) {
    __syncthreads();                       // drains prefetch issued last phase
    const __hip_bfloat16* Kb = &Klds[kts & 1][0];
    const __hip_bfloat16* Vb = &Vlds[kts & 1][0];
    const bool act0 = (kts <= qtab[0]);

    // (1) ALL fragments for this tile -> registers (kf then vf, consumption order)
    bf16x8 kf[2][4];
#pragma unroll
    for (int kk = 0; kk < 2; kk++)
#pragma unroll
      for (int ns = 0; ns < 4; ns++)
        kf[kk][ns] = *(const bf16x8*)(Kb + (ns * 16 + fm) * 64 + (((kk * 4 + g4) ^ (fm & 7)) << 3));
    bf16x4 vf[4][4];
#pragma unroll
    for (int dd = 0; dd < 4; dd++)
#pragma unroll
      for (int ns = 0; ns < 4; ns++)
        vf[dd][ns] = *(const bf16x4*)(Vb + (dd * 16 + fm) * 64 +
                                      (((2 * ns + (g4 >> 1)) ^ (fm & 7)) << 3) + (g4 & 1) * 4);

    // (2) prefetch next tile into the other buffer (no DS ops follow this phase)
    if (kts < lastt) stage(kts + 1, (kts + 1) & 1);

    // (3) compute purely from registers
    f32x4 st1[4], st0[4];
#pragma unroll
    for (int ns = 0; ns < 4; ns++) {
      st1[ns] = (f32x4){0.f, 0.f, 0.f, 0.f};
      st0[ns] = (f32x4){0.f, 0.f, 0.f, 0.f};
    }
#pragma unroll
    for (int kk = 0; kk < 2; kk++) {
#pragma unroll
      for (int ns = 0; ns < 4; ns++)
        st1[ns] = __builtin_amdgcn_mfma_f32_16x16x32_bf16(kf[kk][ns], qf[1][kk], st1[ns], 0, 0, 0);
      if (act0)
#pragma unroll
        for (int ns = 0; ns < 4; ns++)
          st0[ns] = __builtin_amdgcn_mfma_f32_16x16x32_bf16(kf[kk][ns], qf[0][kk], st0[ns], 0, 0, 0);
    }

    auto half = [&](const f32x4 (&st)[4], int hh) {
      const bool diag = (kts == qtab[hh]);
#pragma unroll
      for (int ns = 0; ns < 4; ns++) {
        float e[4];
#pragma unroll
        for (int r = 0; r < 4; r++) {
          float p = __builtin_amdgcn_exp2f(st[ns][r]);
          if (diag) {
            int ktl = ns * 16 + g4 * 4 + r;
            p = (ktl > w * 16 + fm) ? 0.f : p;
          }
          e[r] = p;
        }
        unsigned lo = __builtin_amdgcn_perm(__builtin_bit_cast(unsigned, e[1]),
                                            __builtin_bit_cast(unsigned, e[0]), 0x07060302u);
        unsigned hi = __builtin_amdgcn_perm(__builtin_bit_cast(unsigned, e[3]),
                                            __builtin_bit_cast(unsigned, e[2]), 0x07060302u);
        uint2 pp; pp.x = lo; pp.y = hi;
        bf16x4 pf = __builtin_bit_cast(bf16x4, pp);
        lacc[hh] = __builtin_amdgcn_mfma_f32_16x16x16bf16_1k(pf, ones4, lacc[hh], 0, 0, 0);
#pragma unroll
        for (int dd = 0; dd < 4; dd++)
          acc[hh][dd] = __builtin_amdgcn_mfma_f32_16x16x16bf16_1k(pf, vf[dd][ns], acc[hh][dd], 0, 0, 0);
      }
    };
    half(st1, 1);
    if (act0) half(st0, 0);
  }

  // epilogue: ctx = acc * rcp(l)
#pragma unroll
  for (int hh = 0; hh < 2; hh++) {
    float rl[4];
#pragma unroll
    for (int r = 0; r < 4; r++) rl[r] = __builtin_amdgcn_rcpf(lacc[hh][r]);
#pragma unroll
    for (int dd = 0; dd < 4; dd++)
#pragma unroll
      for (int r = 0; r < 4; r++) {
        int q = qtab[hh] * 64 + w * 16 + g4 * 4 + r;
        ctx[(rowb + q) * 1024 + h * 64 + dd * 16 + fm] =
            __float2bfloat16(acc[hh][dd][r] * rl[r]);
      }
  }
}

// ---------------- launch ----------------
extern "C" void kernel_launch(void* const* d_in, const int* in_sizes, int n_in,
                              void* d_out, int out_size, void* d_ws, size_t ws_size,
                              hipStream_t stream) {
  const float* x  = (const float*)d_in[0];
  const float* Wq = (const float*)d_in[1];
  const float* Wk = (const float*)d_in[2];
  const float* Wv = (const float*)d_in[3];
  const float* Wo = (const float*)d_in[4];
  const float* bo = (const float*)d_in[5];
  float* out = (float*)d_out;

  char* ws = (char*)d_ws;
  __hip_bfloat16* xb     = (__hip_bfloat16*)(ws);                      // 8 MiB
  __hip_bfloat16* Wqkv_t = (__hip_bfloat16*)(ws + (8ull  << 20));      // 6 MiB
  __hip_bfloat16* Wo_t   = (__hip_bfloat16*)(ws + (14ull << 20));      // 2 MiB
  __hip_bfloat16* QKV    = (__hip_bfloat16*)(ws + (16ull << 20));      // 24 MiB (V cols unused)
  __hip_bfloat16* ctxb   = (__hip_bfloat16*)(ws + (40ull << 20));      // 8 MiB
  __hip_bfloat16* Vt     = (__hip_bfloat16*)(ws + (48ull << 20));      // 8 MiB

  prep_kernel<<<dim3(8192), dim3(256), 0, stream>>>(x, xb, Wq, Wk, Wv, Wo, Wqkv_t, Wo_t);
  gemm_kernel<128, true, 2, true><<<dim3(24, 32), dim3(256), 0, stream>>>(
      xb, Wqkv_t, (void*)QKV, nullptr, 3072, Vt);
  attn_kernel<<<dim3(512), dim3(256), 0, stream>>>(QKV, Vt, ctxb);
  gemm_kernel<64, false, 2, false><<<dim3(16, 32), dim3(256), 0, stream>>>(
      ctxb, Wo_t, (void*)out, bo, 1024, nullptr);
}

// Round 16
// 161.633 us; speedup vs baseline: 1.0760x; 1.0073x over previous
//
#include <hip/hip_runtime.h>
#include <hip/hip_bf16.h>
#include <stdint.h>

#define SEQ    2048
#define BATCH  2
#define DMODEL 1024
#define NHEADS 16
#define HDIM   64
#define MROWS  (BATCH*SEQ)   // 4096

typedef __attribute__((ext_vector_type(8))) short bf16x8;
typedef __attribute__((ext_vector_type(4))) short bf16x4;
typedef __attribute__((ext_vector_type(4))) float f32x4;

__device__ inline void global_to_lds16(const void* g, void* l) {
  __builtin_amdgcn_global_load_lds(
      (const __attribute__((address_space(1))) uint32_t*)g,
      (__attribute__((address_space(3))) uint32_t*)l, 16, 0, 0);
}

__device__ inline unsigned short f2bf_bits(float f) {
  __hip_bfloat16 h = __float2bfloat16(f);
  return *(unsigned short*)&h;
}

// ---- prep: x->bf16 (blocks 0..4095) + W transposes (blocks 4096..8191) ----
__global__ void prep_kernel(const float* __restrict__ x, __hip_bfloat16* __restrict__ xb,
                            const float* __restrict__ Wq, const float* __restrict__ Wk,
                            const float* __restrict__ Wv, const float* __restrict__ Wo,
                            __hip_bfloat16* __restrict__ Wqkv_t, __hip_bfloat16* __restrict__ Wo_t) {
  __shared__ float tile[32][33];
  if (blockIdx.x < 4096) {
    int i = (blockIdx.x * 256 + threadIdx.x) * 4;
    float4 v = *(const float4*)(x + i);
    ushort4 o;
    o.x = f2bf_bits(v.x); o.y = f2bf_bits(v.y);
    o.z = f2bf_bits(v.z); o.w = f2bf_bits(v.w);
    *(ushort4*)(xb + i) = o;
    return;
  }
  int idx = blockIdx.x - 4096;
  int z = idx >> 10;
  int rem = idx & 1023;
  const float* W = (z == 0) ? Wq : (z == 1) ? Wk : (z == 2) ? Wv : Wo;
  __hip_bfloat16* dst = (z < 3) ? (Wqkv_t + (size_t)z * 1024 * 1024) : Wo_t;
  int k0 = (rem & 31) * 32, n0 = (rem >> 5) * 32;
  int tx = threadIdx.x & 31, ty = threadIdx.x >> 5;
#pragma unroll
  for (int r = 0; r < 4; r++)
    tile[ty + r * 8][tx] = W[(size_t)(k0 + ty + r * 8) * 1024 + n0 + tx];
  __syncthreads();
#pragma unroll
  for (int r = 0; r < 4; r++)
    dst[(size_t)(n0 + ty + r * 8) * 1024 + k0 + tx] = __float2bfloat16(tile[tx][ty + r * 8]);
}

// ------ GEMM: C[M][ldc] = A[M][1024]*Wt[N][1024]^T (+bias), BK=64, dbuf LDS ------
// Register-staged phases (R14 pattern). FUSE_VT: V projection written transposed.
template <int TN, bool OUT_BF16, int MINW, bool FUSE_VT>
__global__ __launch_bounds__(256, MINW)
void gemm_kernel(const __hip_bfloat16* __restrict__ A, const __hip_bfloat16* __restrict__ Bt,
                 void* __restrict__ C, const float* __restrict__ bias, int ldc,
                 __hip_bfloat16* __restrict__ Vt) {
  __shared__ __hip_bfloat16 Asl[2][128 * 64];
  __shared__ __hip_bfloat16 Bsl[2][TN * 64];

  const int t = threadIdx.x;
  const int lane = t & 63;
  const int w = t >> 6;
  constexpr int MI = (TN == 128) ? 4 : 2;
  const int wrow = (TN == 128) ? (w >> 1) * 64 : w * 32;
  const int wcol = (TN == 128) ? (w & 1) * 64 : 0;
  const int m0 = blockIdx.y * 128;
  const int n0 = blockIdx.x * TN;

  f32x4 acc[MI][4];
#pragma unroll
  for (int i = 0; i < MI; i++)
#pragma unroll
    for (int j = 0; j < 4; j++) acc[i][j] = (f32x4){0.f, 0.f, 0.f, 0.f};

  const int srow = lane >> 3;
  const int sjc = (lane & 7) ^ srow;
  const int fm = lane & 15;
  const int g4 = lane >> 4;

  auto stage = [&](int k0, int bufi) {
#pragma unroll
    for (int i = 0; i < 4; i++) {
      int seg = i * 4 + w;
      int r = seg * 8 + srow;
      global_to_lds16(A + (size_t)(m0 + r) * 1024 + k0 + sjc * 8,
                      (void*)(&Asl[bufi][0] + seg * 512 + lane * 8));
    }
#pragma unroll
    for (int i = 0; i < TN / 32; i++) {
      int seg = i * 4 + w;
      int r = seg * 8 + srow;
      global_to_lds16(Bt + (size_t)(n0 + r) * 1024 + k0 + sjc * 8,
                      (void*)(&Bsl[bufi][0] + seg * 512 + lane * 8));
    }
  };

  stage(0, 0);
  for (int k0 = 0; k0 < 1024; k0 += 64) {
    const int buf = (k0 >> 6) & 1;
    __syncthreads();

    bf16x8 af[2][MI], bfr[2][4];
#pragma unroll
    for (int kb = 0; kb < 2; kb++) {
#pragma unroll
      for (int mi = 0; mi < MI; mi++) {
        int row = wrow + mi * 16 + fm;
        af[kb][mi] = *(const bf16x8*)(&Asl[buf][0] + row * 64 + (((kb * 4 + g4) ^ (row & 7)) << 3));
      }
#pragma unroll
      for (int ni = 0; ni < 4; ni++) {
        int row = wcol + ni * 16 + fm;
        bfr[kb][ni] = *(const bf16x8*)(&Bsl[buf][0] + row * 64 + (((kb * 4 + g4) ^ (row & 7)) << 3));
      }
    }

    if (k0 + 64 < 1024) stage(k0 + 64, buf ^ 1);

#pragma unroll
    for (int kb = 0; kb < 2; kb++)
#pragma unroll
      for (int mi = 0; mi < MI; mi++)
#pragma unroll
        for (int ni = 0; ni < 4; ni++)
          acc[mi][ni] = __builtin_amdgcn_mfma_f32_16x16x32_bf16(af[kb][mi], bfr[kb][ni], acc[mi][ni], 0, 0, 0);
  }

  const bool vt_block = FUSE_VT && (n0 >= 2048);
#pragma unroll
  for (int mi = 0; mi < MI; mi++) {
    int mb = m0 + wrow + mi * 16 + g4 * 4;
#pragma unroll
    for (int ni = 0; ni < 4; ni++) {
      int n = n0 + wcol + ni * 16 + fm;
      if (vt_block) {
        int nv = n - 2048;
        int bhh = (mb >> 11) * 16 + (nv >> 6);
        int d = nv & 63;
        int s = mb & 2047;
        unsigned short u[4];
#pragma unroll
        for (int r = 0; r < 4; r++) u[r] = f2bf_bits(acc[mi][ni][r]);
        *(ushort4*)(Vt + ((size_t)bhh * 64 + d) * 2048 + s) = *(const ushort4*)u;
      } else {
        float bv = OUT_BF16 ? 0.f : bias[n];
#pragma unroll
        for (int r = 0; r < 4; r++) {
          if (OUT_BF16)
            ((__hip_bfloat16*)C)[(size_t)(mb + r) * ldc + n] = __float2bfloat16(acc[mi][ni][r]);
          else
            ((float*)C)[(size_t)(mb + r) * ldc + n] = acc[mi][ni][r] + bv;
        }
      }
    }
  }
}

// ---- causal flash attention: paired q-tiles, 128-kt split-fragment phases ----
// Phase (128 kt, one barrier): load sub0 frags -> prefetch(pt+1) -> compute sub0
// -> load sub1 frags (forced partial drain lands mid-phase, when the prefetch
// already has ~a sub-phase of flight) -> compute sub1. Barriers halve vs 64-kt;
// the full drain at the barrier gets a whole phase of flight. R14 rule otherwise
// respected: fragments to registers before compute; no DS op between prefetch
// and the (intentional) sub1 reload point.
__global__ __launch_bounds__(256, 2)
void attn_kernel(const __hip_bfloat16* __restrict__ QKV,
                 const __hip_bfloat16* __restrict__ Vt,
                 __hip_bfloat16* __restrict__ ctx) {
  __shared__ __hip_bfloat16 Klds[2][128 * 64];   // [buf][kt][d], chunk j at slot j^(row&7)
  __shared__ __hip_bfloat16 Vlds[2][64 * 128];   // [buf][d][kt], chunk j at slot j^(d&7)

  const int t = threadIdx.x;
  const int lane = t & 63;
  const int w = t >> 6;                    // 0..3
  const int L = blockIdx.x;                // 0..511
  const int bh = (L & 7) + 8 * ((L >> 3) & 3);   // 4 bh per XCD (wgid%8 heuristic)
  const int jraw = L >> 5;                       // 0..15
  const int jb = (jraw < 8) ? jraw : 23 - jraw;  // co-resident complementary pairs
  const int qtab[2] = { jb, 31 - jb };
  const int b = bh >> 4, h = bh & 15;
  const int fm = lane & 15;
  const int g4 = lane >> 4;
  const int fk = g4 * 8;
  const size_t rowb = (size_t)b * SEQ;
  const float c = 0.18033688011112042f;    // log2(e)/8

  const int krr = lane >> 3;               // 0..7
  const int kjc = (lane & 7) ^ krr;        // K staging swizzle
  const int vrr = lane >> 4;               // 0..3

  // Q fragments (MFMA B operands), prescaled by c
  bf16x8 qf[2][2];
#pragma unroll
  for (int hh = 0; hh < 2; hh++) {
    const __hip_bfloat16* qp = QKV + (rowb + qtab[hh] * 64 + w * 16 + fm) * 3072 + h * 64 + fk;
    bf16x8 r0 = *(const bf16x8*)qp;
    bf16x8 r1 = *(const bf16x8*)(qp + 32);
#pragma unroll
    for (int i = 0; i < 8; i++) {
      float f0 = __uint_as_float(((unsigned)(unsigned short)r0[i]) << 16) * c;
      float f1 = __uint_as_float(((unsigned)(unsigned short)r1[i]) << 16) * c;
      r0[i] = (short)f2bf_bits(f0);
      r1[i] = (short)f2bf_bits(f1);
    }
    qf[hh][0] = r0; qf[hh][1] = r1;
  }

  bf16x4 ones4;
#pragma unroll
  for (int i = 0; i < 4; i++) ones4[i] = (short)0x3F80;

  f32x4 acc[2][4];
  f32x4 lacc[2];
#pragma unroll
  for (int hh = 0; hh < 2; hh++) {
    lacc[hh] = (f32x4){0.f, 0.f, 0.f, 0.f};
#pragma unroll
    for (int d = 0; d < 4; d++) acc[hh][d] = (f32x4){0.f, 0.f, 0.f, 0.f};
  }

  // stage one 128-kt phase: K 16KB (16 segs x 8 rows) + V 16KB (16 segs x 4 d-rows)
  auto stage = [&](int pt, int bufi) {
    const int kt0 = pt * 128;
#pragma unroll
    for (int i = 0; i < 4; i++) {
      int seg = i * 4 + w;                 // 0..15
      int kr = seg * 8 + krr;              // K row 0..127
      global_to_lds16(QKV + (rowb + kt0 + kr) * 3072 + 1024 + h * 64 + kjc * 8,
                      (void*)(&Klds[bufi][0] + seg * 512 + lane * 8));
      int vd = seg * 4 + vrr;              // Vt d-row 0..63
      int vjc = (lane & 15) ^ ((seg & 1) * 4 + vrr);
      global_to_lds16(Vt + ((size_t)bh * 64 + vd) * 2048 + kt0 + vjc * 8,
                      (void*)(&Vlds[bufi][0] + seg * 512 + lane * 8));
    }
  };

  // compute one 64-kt sub-tile from pre-loaded fragments
  auto subcompute = [&](const bf16x8 (&kf)[2][4], const bf16x4 (&vf)[4][4], int kts) {
    const bool act0 = (kts <= qtab[0]);
    f32x4 st1[4], st0[4];
#pragma unroll
    for (int ns = 0; ns < 4; ns++) {
      st1[ns] = (f32x4){0.f, 0.f, 0.f, 0.f};
      st0[ns] = (f32x4){0.f, 0.f, 0.f, 0.f};
    }
#pragma unroll
    for (int kk = 0; kk < 2; kk++) {
#pragma unroll
      for (int ns = 0; ns < 4; ns++)
        st1[ns] = __builtin_amdgcn_mfma_f32_16x16x32_bf16(kf[kk][ns], qf[1][kk], st1[ns], 0, 0, 0);
      if (act0)
#pragma unroll
        for (int ns = 0; ns < 4; ns++)
          st0[ns] = __builtin_amdgcn_mfma_f32_16x16x32_bf16(kf[kk][ns], qf[0][kk], st0[ns], 0, 0, 0);
    }
    auto half = [&](const f32x4 (&st)[4], int hh) {
      const bool diag = (kts == qtab[hh]);
#pragma unroll
      for (int ns = 0; ns < 4; ns++) {
        float e[4];
#pragma unroll
        for (int r = 0; r < 4; r++) {
          float p = __builtin_amdgcn_exp2f(st[ns][r]);
          if (diag) {
            int ktl = ns * 16 + g4 * 4 + r;
            p = (ktl > w * 16 + fm) ? 0.f : p;
          }
          e[r] = p;
        }
        unsigned lo = __builtin_amdgcn_perm(__builtin_bit_cast(unsigned, e[1]),
                                            __builtin_bit_cast(unsigned, e[0]), 0x07060302u);
        unsigned hi = __builtin_amdgcn_perm(__builtin_bit_cast(unsigned, e[3]),
                                            __builtin_bit_cast(unsigned, e[2]), 0x07060302u);
        uint2 pp; pp.x = lo; pp.y = hi;
        bf16x4 pf = __builtin_bit_cast(bf16x4, pp);
        lacc[hh] = __builtin_amdgcn_mfma_f32_16x16x16bf16_1k(pf, ones4, lacc[hh], 0, 0, 0);
#pragma unroll
        for (int dd = 0; dd < 4; dd++)
          acc[hh][dd] = __builtin_amdgcn_mfma_f32_16x16x16bf16_1k(pf, vf[dd][ns], acc[hh][dd], 0, 0, 0);
      }
    };
    half(st1, 1);
    if (act0) half(st0, 0);
  };

  // fragment loaders for sub-tile sc of the current buffer
  auto load_kf = [&](const __hip_bfloat16* Kb, int sc, bf16x8 (&kf)[2][4]) {
#pragma unroll
    for (int kk = 0; kk < 2; kk++)
#pragma unroll
      for (int ns = 0; ns < 4; ns++) {
        int row = sc * 64 + ns * 16 + fm;
        kf[kk][ns] = *(const bf16x8*)(Kb + row * 64 + (((kk * 4 + g4) ^ (fm & 7)) << 3));
      }
  };
  auto load_vf = [&](const __hip_bfloat16* Vb, int sc, bf16x4 (&vf)[4][4]) {
#pragma unroll
    for (int dd = 0; dd < 4; dd++)
#pragma unroll
      for (int ns = 0; ns < 4; ns++) {
        int ch = sc * 8 + ns * 2 + (g4 >> 1);
        vf[dd][ns] = *(const bf16x4*)(Vb + (dd * 16 + fm) * 128 +
                                      ((ch ^ (fm & 7)) << 3) + (g4 & 1) * 4);
      }
  };

  const int lastt = qtab[1];               // 24..31 or 16..23
  const int lastp = lastt >> 1;
  stage(0, 0);
  for (int pt = 0; pt <= lastp; ++pt) {
    __syncthreads();                       // drains prefetch issued last phase
    const int buf = pt & 1;
    const __hip_bfloat16* Kb = &Klds[buf][0];
    const __hip_bfloat16* Vb = &Vlds[buf][0];

    // sub0: fragments -> registers, then prefetch, then compute
    bf16x8 kf[2][4];
    bf16x4 vf[4][4];
    load_kf(Kb, 0, kf);
    load_vf(Kb == Kb ? Vb : Vb, 0, vf);    // (plain call; keeps source order)
    if (pt < lastp) stage(pt + 1, buf ^ 1);
    subcompute(kf, vf, pt * 2);

    // sub1: reload fragments (partial drain lands here with ~a sub-phase of flight)
    if (pt * 2 + 1 <= lastt) {
      load_kf(Kb, 1, kf);
      load_vf(Vb, 1, vf);
      subcompute(kf, vf, pt * 2 + 1);
    }
  }

  // epilogue: ctx = acc * rcp(l)
#pragma unroll
  for (int hh = 0; hh < 2; hh++) {
    float rl[4];
#pragma unroll
    for (int r = 0; r < 4; r++) rl[r] = __builtin_amdgcn_rcpf(lacc[hh][r]);
#pragma unroll
    for (int dd = 0; dd < 4; dd++)
#pragma unroll
      for (int r = 0; r < 4; r++) {
        int q = qtab[hh] * 64 + w * 16 + g4 * 4 + r;
        ctx[(rowb + q) * 1024 + h * 64 + dd * 16 + fm] =
            __float2bfloat16(acc[hh][dd][r] * rl[r]);
      }
  }
}

// ---------------- launch ----------------
extern "C" void kernel_launch(void* const* d_in, const int* in_sizes, int n_in,
                              void* d_out, int out_size, void* d_ws, size_t ws_size,
                              hipStream_t stream) {
  const float* x  = (const float*)d_in[0];
  const float* Wq = (const float*)d_in[1];
  const float* Wk = (const float*)d_in[2];
  const float* Wv = (const float*)d_in[3];
  const float* Wo = (const float*)d_in[4];
  const float* bo = (const float*)d_in[5];
  float* out = (float*)d_out;

  char* ws = (char*)d_ws;
  __hip_bfloat16* xb     = (__hip_bfloat16*)(ws);                      // 8 MiB
  __hip_bfloat16* Wqkv_t = (__hip_bfloat16*)(ws + (8ull  << 20));      // 6 MiB
  __hip_bfloat16* Wo_t   = (__hip_bfloat16*)(ws + (14ull << 20));      // 2 MiB
  __hip_bfloat16* QKV    = (__hip_bfloat16*)(ws + (16ull << 20));      // 24 MiB (V cols unused)
  __hip_bfloat16* ctxb   = (__hip_bfloat16*)(ws + (40ull << 20));      // 8 MiB
  __hip_bfloat16* Vt     = (__hip_bfloat16*)(ws + (48ull << 20));      // 8 MiB

  prep_kernel<<<dim3(8192), dim3(256), 0, stream>>>(x, xb, Wq, Wk, Wv, Wo, Wqkv_t, Wo_t);
  gemm_kernel<128, true, 2, true><<<dim3(24, 32), dim3(256), 0, stream>>>(
      xb, Wqkv_t, (void*)QKV, nullptr, 3072, Vt);
  attn_kernel<<<dim3(512), dim3(256), 0, stream>>>(QKV, Vt, ctxb);
  gemm_kernel<64, false, 2, false><<<dim3(16, 32), dim3(256), 0, stream>>>(
      ctxb, Wo_t, (void*)out, bo, 1024, nullptr);
}